// Round 15
// baseline (534.057 us; speedup 1.0000x reference)
//
#include <hip/hip_runtime.h>
#include <math.h>
#include <float.h>

// Problem constants (from reference)
#define NB 2
#define LQ 2048
#define HH 8
#define EE 64
#define SS 2048
#define CC 256
#define KM_ITERS 10
#define NBITS 32
#define TK 32
#define NH (NB*HH)
#define CG 4    // clusters per k_rows block

// ---------------- K1: hash bits -> 32-bit mask per (n,h,l) ----------------
__global__ __launch_bounds__(256) void k_hash(const float* __restrict__ Q,
                                              const float* __restrict__ planes,
                                              unsigned int* __restrict__ qmask) {
    int gid = blockIdx.x * 256 + threadIdx.x;      // nh*LQ + l
    int nh = gid >> 11, l = gid & (LQ - 1);
    int n = nh >> 3, h = nh & 7;
    const float* qrow = Q + (((size_t)n * LQ + l) * HH + h) * EE;
    float q[64];
    #pragma unroll
    for (int e = 0; e < 64; e++) q[e] = qrow[e];
    unsigned int m = 0;
    for (int b = 0; b < NBITS; b++) {
        double acc = (double)planes[b * 65 + 64];   // bias
        #pragma unroll
        for (int e = 0; e < 64; e++) acc += (double)q[e] * (double)planes[b * 65 + e];
        if (acc > 0.0) m |= (1u << b);
    }
    qmask[gid] = m;
}

// ---------------- K2 mono: full k-means per nh in ONE kernel (16 blocks x 1024) ------
// Replaces cinit + 11x assign + 10x update + finalize (23 graph nodes -> 1).
// All state in LDS; decisions exact-integer identical to the split chain:
// packed (d<<8)|c min == jnp.argmin first-min; majority 2*bs>=cnt exact.
__global__ __launch_bounds__(1024) void k_kmeans_mono(const unsigned int* __restrict__ qmask,
                                                      int* __restrict__ clusters,
                                                      int* __restrict__ counts_out,
                                                      int* __restrict__ order_out,
                                                      int* __restrict__ offsets_out) {
    int nh = blockIdx.x;
    int t = threadIdx.x;                              // 0..1023
    __shared__ __align__(16) unsigned int cent[CC];   // 1KB
    __shared__ unsigned int sortedm[LQ];              // 8KB (masks, cluster-grouped)
    __shared__ int cnts[CC], offs[CC], cursor[CC];    // 3KB

    const unsigned int* qb = qmask + (size_t)nh * LQ;
    unsigned int m0 = qb[t], m1 = qb[t + 1024];
    if (t < CC) cent[t] = qb[t * 8];                  // init_idx = c*8
    __syncthreads();

    int bc0 = 0, bc1 = 0;
    for (int it = 0; it <= KM_ITERS; ++it) {
        // ---- assign: packed-min, 2 points/thread ----
        int b0 = 0x7fffffff, b1 = 0x7fffffff;
        const uint4* c4p = (const uint4*)cent;
        #pragma unroll 4
        for (int c4 = 0; c4 < CC / 4; c4++) {
            uint4 cm = c4p[c4];
            int base = c4 << 2;
            int e;
            e = (__popc(m0 ^ cm.x) << 8) + base;     b0 = b0 < e ? b0 : e;
            e = (__popc(m0 ^ cm.y) << 8) + base + 1; b0 = b0 < e ? b0 : e;
            e = (__popc(m0 ^ cm.z) << 8) + base + 2; b0 = b0 < e ? b0 : e;
            e = (__popc(m0 ^ cm.w) << 8) + base + 3; b0 = b0 < e ? b0 : e;
            e = (__popc(m1 ^ cm.x) << 8) + base;     b1 = b1 < e ? b1 : e;
            e = (__popc(m1 ^ cm.y) << 8) + base + 1; b1 = b1 < e ? b1 : e;
            e = (__popc(m1 ^ cm.z) << 8) + base + 2; b1 = b1 < e ? b1 : e;
            e = (__popc(m1 ^ cm.w) << 8) + base + 3; b1 = b1 < e ? b1 : e;
        }
        bc0 = b0 & 255; bc1 = b1 & 255;
        if (it == KM_ITERS) break;                    // 11th pass = final assign only

        // ---- counting sort (masks grouped by cluster) ----
        __syncthreads();                              // prior update reads done
        if (t < CC) cnts[t] = 0;
        __syncthreads();
        atomicAdd(&cnts[bc0], 1); atomicAdd(&cnts[bc1], 1);
        __syncthreads();
        if (t < 64) {                                 // single-wave exclusive scan
            int c0 = cnts[4 * t], c1 = cnts[4 * t + 1], c2 = cnts[4 * t + 2], c3 = cnts[4 * t + 3];
            int s1 = c0 + c1, s2 = s1 + c2, tot = s2 + c3;
            int inc = tot;
            #pragma unroll
            for (int o = 1; o < 64; o <<= 1) {
                int v = __shfl_up(inc, o);
                if (t >= o) inc += v;
            }
            int excl = inc - tot;
            offs[4 * t] = excl;          cursor[4 * t] = excl;
            offs[4 * t + 1] = excl + c0; cursor[4 * t + 1] = excl + c0;
            offs[4 * t + 2] = excl + s1; cursor[4 * t + 2] = excl + s1;
            offs[4 * t + 3] = excl + s2; cursor[4 * t + 3] = excl + s2;
        }
        __syncthreads();
        { int p0 = atomicAdd(&cursor[bc0], 1); sortedm[p0] = m0; }
        { int p1 = atomicAdd(&cursor[bc1], 1); sortedm[p1] = m1; }
        __syncthreads();

        // ---- update: 4 slots per cluster, shfl-combined exact majority ----
        int c = t >> 2, slot = t & 3;
        int cnt_c = cnts[c], off_c = offs[c];
        int bs[32];
        #pragma unroll
        for (int b = 0; b < 32; b++) bs[b] = 0;
        for (int i = slot; i < cnt_c; i += 4) {
            unsigned int mm = sortedm[off_c + i];
            #pragma unroll
            for (int b = 0; b < 32; b++) bs[b] += (mm >> b) & 1;
        }
        #pragma unroll
        for (int b = 0; b < 32; b++) {
            bs[b] += __shfl_xor(bs[b], 1);
            bs[b] += __shfl_xor(bs[b], 2);
        }
        if (slot == 0 && cnt_c > 0) {
            unsigned int nc = 0;
            #pragma unroll
            for (int b = 0; b < 32; b++) if (2 * bs[b] >= cnt_c) nc |= (1u << b);
            cent[c] = nc;                             // exact majority; keep old if cnt==0
        }
        __syncthreads();
    }

    // ---- finalize: clusters, counts, offsets, order ----
    clusters[(size_t)nh * LQ + t] = bc0;
    clusters[(size_t)nh * LQ + t + 1024] = bc1;
    __syncthreads();
    if (t < CC) cnts[t] = 0;
    __syncthreads();
    atomicAdd(&cnts[bc0], 1); atomicAdd(&cnts[bc1], 1);
    __syncthreads();
    if (t < 64) {
        int c0 = cnts[4 * t], c1 = cnts[4 * t + 1], c2 = cnts[4 * t + 2], c3 = cnts[4 * t + 3];
        int s1 = c0 + c1, s2 = s1 + c2, tot = s2 + c3;
        int inc = tot;
        #pragma unroll
        for (int o = 1; o < 64; o <<= 1) {
            int v = __shfl_up(inc, o);
            if (t >= o) inc += v;
        }
        int excl = inc - tot;
        offs[4 * t] = excl;          cursor[4 * t] = excl;
        offs[4 * t + 1] = excl + c0; cursor[4 * t + 1] = excl + c0;
        offs[4 * t + 2] = excl + s1; cursor[4 * t + 2] = excl + s1;
        offs[4 * t + 3] = excl + s2; cursor[4 * t + 3] = excl + s2;
    }
    __syncthreads();
    if (t < CC) {
        counts_out[nh * CC + t] = cnts[t];
        offsets_out[nh * CC + t] = offs[t];
    }
    { int p0 = atomicAdd(&cursor[bc0], 1); order_out[(size_t)nh * LQ + p0] = t; }
    { int p1 = atomicAdd(&cursor[bc1], 1); order_out[(size_t)nh * LQ + p1] = t + 1024; }
}

// ---------------- K3: segmented cluster-mean Qg (f64), wave per cluster ----------------
__global__ __launch_bounds__(256) void k_qg(const float* __restrict__ Q,
                                            const int* __restrict__ order,
                                            const int* __restrict__ offsets,
                                            const int* __restrict__ counts,
                                            double* __restrict__ Qg) {
    int nh = blockIdx.x >> 6;              // 64 blocks per nh
    int c = (blockIdx.x & 63) * 4 + (threadIdx.x >> 6);
    int e = threadIdx.x & 63;
    int n = nh >> 3, h = nh & 7;
    int off = offsets[nh * CC + c];
    int cnt = counts[nh * CC + c];
    const int* ord = order + (size_t)nh * LQ + off;
    double acc = 0.0;
    for (int i = 0; i < cnt; i++) {
        int p = ord[i];                    // wave-uniform broadcast read
        acc += (double)Q[(((size_t)n * LQ + p) * HH + h) * EE + e];
    }
    double safe = cnt > 0 ? (double)cnt : 1.0;
    Qg[((size_t)(nh * CC + c)) * EE + e] = acc / safe;
}

// ---------------- K3b: transpose K -> Kt[nh][e][s] ----------------
__global__ __launch_bounds__(256) void k_transpose(const float* __restrict__ Kp,
                                                   float* __restrict__ Kt) {
    int nh = blockIdx.x >> 5;              // 32 s-tiles of 64
    int s0 = (blockIdx.x & 31) * 64;
    int n = nh >> 3, h = nh & 7;
    __shared__ float tile[64][65];
    int t = threadIdx.x;
    int e = t & 63, r0 = t >> 6;
    #pragma unroll
    for (int j = 0; j < 16; j++) {
        int r = r0 * 16 + j;
        tile[r][e] = Kp[(((size_t)n * SS + s0 + r) * HH + h) * EE + e];
    }
    __syncthreads();
    int sl = t & 63, eg = t >> 6;
    #pragma unroll
    for (int j = 0; j < 16; j++) {
        int ee_ = eg * 16 + j;
        Kt[((size_t)nh * EE + ee_) * SS + s0 + sl] = tile[sl][ee_];
    }
}

// ---------------- K4 v9 (R14): chunked LDS transpose (18KB) + XCD swizzle, f64 -------
__global__ __launch_bounds__(256) void k_rows(const float* __restrict__ Kt,
                                              const float* __restrict__ Vp,
                                              const double* __restrict__ Qg,
                                              int* __restrict__ topi,
                                              float* __restrict__ abk,
                                              float* __restrict__ Vg) {
    int bid = blockIdx.x;
    int xcd = bid & 7, idx = bid >> 3;     // XCD-chunked: xcd owns 2 nh slices (L2-local)
    int nh = xcd * 2 + (idx >> 6);
    int cg = idx & 63;
    int c0 = cg * CG;
    int n = nh >> 3, h = nh & 7;
    int t = threadIdx.x, w = t >> 6, l = t & 63;

    __shared__ double qgl[EE][CG];         // 2KB
    __shared__ double xrowc[CG][512];      // 16KB chunk buffer (reused 4x)
    float* wbuf = (float*)&xrowc[0][0];    // [512][CG] f32 = 8KB overlay
    float* redv = (float*)&xrowc[2][0];    // 4KB (disjoint from wbuf)

    qgl[t >> 2][t & 3] = Qg[((size_t)(nh * CC + c0 + (t & 3))) * EE + (t >> 2)];
    __syncthreads();

    // ---- phase A: QK scores (f64) in registers, coalesced Kt reads ----
    double acc[8][CG];
    #pragma unroll
    for (int r = 0; r < 8; r++)
        #pragma unroll
        for (int c = 0; c < CG; c++) acc[r][c] = 0.0;
    const float* ktb = Kt + ((size_t)nh * EE) * SS + t;
    for (int e = 0; e < EE; e++) {
        double q0 = qgl[e][0], q1 = qgl[e][1], q2 = qgl[e][2], q3 = qgl[e][3];
        const float* kr = ktb + (size_t)e * SS;
        #pragma unroll
        for (int r = 0; r < 8; r++) {
            double kv = (double)kr[r * 256];
            acc[r][0] += q0 * kv; acc[r][1] += q1 * kv;
            acc[r][2] += q2 * kv; acc[r][3] += q3 * kv;
        }
    }

    // ---- chunked transpose: acc -> v[32] (v[k] = score(c=w, s=l+64k)) ----
    double v[32];
    #pragma unroll
    for (int j = 0; j < 4; j++) {
        __syncthreads();
        #pragma unroll
        for (int c = 0; c < CG; c++) {
            xrowc[c][t]       = acc[2 * j][c];
            xrowc[c][256 + t] = acc[2 * j + 1][c];
        }
        __syncthreads();
        #pragma unroll
        for (int m = 0; m < 8; m++)
            v[8 * j + m] = xrowc[w][((m >> 2) << 8) + ((m & 3) << 6) + l];
    }

    // ---- phase B: max, denom, top-32 (exact f64, ties -> lowest s) ----
    double m = v[0];
    #pragma unroll
    for (int k = 1; k < 32; k++) m = v[k] > m ? v[k] : m;
    #pragma unroll
    for (int o = 32; o > 0; o >>= 1) { double z = __shfl_xor(m, o); m = z > m ? z : m; }

    double ds = 0.0;
    #pragma unroll
    for (int k = 0; k < 32; k++) ds += (double)expf(0.125f * (float)(v[k] - m));
    #pragma unroll
    for (int o = 32; o > 0; o >>= 1) ds += __shfl_xor(ds, o);

    unsigned ext = 0;
    double lbv = -1e301; int lbi = 1 << 30;
    #pragma unroll
    for (int k = 0; k < 32; k++)
        if (v[k] > lbv) { lbv = v[k]; lbi = l + k * 64; }
    double topsum = 0.0;
    int rowid = nh * CC + c0 + w;
    for (int kk = 0; kk < TK; kk++) {
        double bv = lbv; int bi = lbi;
        #pragma unroll
        for (int o = 32; o > 0; o >>= 1) {
            double v2 = __shfl_xor(bv, o); int i2 = __shfl_xor(bi, o);
            if (v2 > bv || (v2 == bv && i2 < bi)) { bv = v2; bi = i2; }
        }
        topsum += (double)expf(0.125f * (float)(bv - m));
        if (l == 0) topi[(size_t)rowid * TK + kk] = bi;
        if ((bi & 63) == l) {
            ext |= 1u << (bi >> 6);
            lbv = -1e301; lbi = 1 << 30;
            #pragma unroll
            for (int k = 0; k < 32; k++)
                if (!((ext >> k) & 1) && v[k] > lbv) { lbv = v[k]; lbi = l + k * 64; }
        }
    }
    if (l == 0) abk[rowid] = (float)((ds - topsum) / ds);

    float invd = (float)(1.0 / ds);
    float w32r[32];
    #pragma unroll
    for (int k = 0; k < 32; k++)
        w32r[k] = ((ext >> k) & 1) ? 0.0f
                : expf(0.125f * (float)(v[k] - m)) * invd;

    // ---- phase C: chunked weight exchange + Vg accumulate ----
    float a0 = 0.f, a1 = 0.f, a2 = 0.f, a3 = 0.f;
    const float* vb = Vp + (((size_t)n * SS) * HH + h) * EE + l;   // e = l
    #pragma unroll
    for (int j = 0; j < 4; j++) {
        __syncthreads();
        #pragma unroll
        for (int m2 = 0; m2 < 8; m2++)
            wbuf[(((m2 << 6) + l) << 2) + w] = w32r[8 * j + m2];
        __syncthreads();
        const float4* wp4 = (const float4*)wbuf;
        int sbase = 512 * j + 128 * w;
        for (int s = 0; s < 128; s++) {
            float4 wv = wp4[128 * w + s];                          // wave-uniform broadcast
            float vv = vb[(size_t)(sbase + s) * HH * EE];          // coalesced (e=l)
            a0 += wv.x * vv; a1 += wv.y * vv; a2 += wv.z * vv; a3 += wv.w * vv;
        }
    }
    {
        int e = l, grp = w;
        redv[(grp * 4 + 0) * 64 + e] = a0;
        redv[(grp * 4 + 1) * 64 + e] = a1;
        redv[(grp * 4 + 2) * 64 + e] = a2;
        redv[(grp * 4 + 3) * 64 + e] = a3;
        __syncthreads();
        int c = w;
        float s = redv[(0 * 4 + c) * 64 + e] + redv[(1 * 4 + c) * 64 + e]
                + redv[(2 * 4 + c) * 64 + e] + redv[(3 * 4 + c) * 64 + e];
        Vg[((size_t)(nh * CC + c0 + c)) * EE + e] = s;
    }
}

// ---------------- K5: per-query top-32 re-attention + V_bottom ----------------
__global__ __launch_bounds__(256) void k_out(const float* __restrict__ Q,
                                             const float* __restrict__ Kp,
                                             const float* __restrict__ Vp,
                                             const int* __restrict__ clusters,
                                             const int* __restrict__ topi,
                                             const float* __restrict__ abk,
                                             const float* __restrict__ Vg,
                                             float* __restrict__ out) {
    int tid = threadIdx.x, wid = tid >> 6, e = tid & 63;
    int q = blockIdx.x * 4 + wid;            // nh*LQ + l
    int nh = q >> 11, l = q & (LQ - 1);
    int n = nh >> 3, h = nh & 7;
    int c = clusters[q];
    float scale = 1.0f - abk[nh * CC + c];
    const int* ti = topi + (size_t)(nh * CC + c) * TK;
    float qe = Q[(((size_t)n * LQ + l) * HH + h) * EE + e];
    float myv = -INFINITY;
    for (int k = 0; k < TK; k++) {
        int idx = ti[k];
        float kv = Kp[(((size_t)n * SS + idx) * HH + h) * EE + e];
        float v = qe * kv;
        #pragma unroll
        for (int o = 32; o > 0; o >>= 1) v += __shfl_xor(v, o);
        if (e == k) myv = v;
    }
    float mv = myv;
    #pragma unroll
    for (int o = 32; o > 0; o >>= 1) { float v = __shfl_xor(mv, o); mv = v > mv ? v : mv; }
    float p = (e < TK) ? expf(0.125f * (myv - mv)) : 0.0f;
    float ssum = p;
    #pragma unroll
    for (int o = 32; o > 0; o >>= 1) ssum += __shfl_xor(ssum, o);
    float at = p / ssum * scale;
    float acc = 0.0f;
    for (int k = 0; k < TK; k++) {
        float wk = __shfl(at, k, 64);
        int idx = ti[k];
        acc += wk * Vp[(((size_t)n * SS + idx) * HH + h) * EE + e];
    }
    acc += Vg[(size_t)(nh * CC + c) * EE + e];
    out[(((size_t)n * LQ + l) * HH + h) * EE + e] = acc;
}

extern "C" void kernel_launch(void* const* d_in, const int* in_sizes, int n_in,
                              void* d_out, int out_size, void* d_ws, size_t ws_size,
                              hipStream_t stream) {
    const float* Q      = (const float*)d_in[0];
    const float* K      = (const float*)d_in[1];
    const float* V      = (const float*)d_in[2];
    const float* planes = (const float*)d_in[3];
    float* out = (float*)d_out;

    char* ws = (char*)d_ws;
    unsigned int* qmask    = (unsigned int*)(ws);                   // 128KB
    int*          clusters = (int*)(ws + (128 << 10));              // 128KB
    int*          counts   = (int*)(ws + (256 << 10));              // 16KB
    float*        abk      = (float*)(ws + (272 << 10));            // 16KB
    int*          topi     = (int*)(ws + (288 << 10));              // 512KB
    float*        Vg       = (float*)(ws + (800 << 10));            // 1MB
    double*       Qg       = (double*)(ws + (1824 << 10));          // 2MB
    float*        Kt       = (float*)(ws + (4096 << 10));           // 8MB  [4MB,12MB)
    int*          order    = (int*)(ws + (12288 << 10));            // 128KB
    int*          offsets  = (int*)(ws + (12416 << 10));            // 16KB

    k_transpose<<<dim3(NH * 32), dim3(256), 0, stream>>>(K, Kt);
    k_hash<<<dim3(NH * LQ / 256), dim3(256), 0, stream>>>(Q, planes, qmask);
    k_kmeans_mono<<<dim3(NH), dim3(1024), 0, stream>>>(qmask, clusters, counts, order, offsets);
    k_qg<<<dim3(NH * 64), dim3(256), 0, stream>>>(Q, order, offsets, counts, Qg);
    k_rows<<<dim3(NH * CC / CG), dim3(256), 0, stream>>>(Kt, V, Qg, topi, abk, Vg);
    k_out<<<dim3(NH * LQ / 4), dim3(256), 0, stream>>>(Q, K, V, clusters, topi, abk, Vg, out);
}

// Round 16
// 418.803 us; speedup vs baseline: 1.2752x; 1.2752x over previous
//
#include <hip/hip_runtime.h>
#include <math.h>
#include <float.h>

// Problem constants (from reference)
#define NB 2
#define LQ 2048
#define HH 8
#define EE 64
#define SS 2048
#define CC 256
#define KM_ITERS 10
#define NBITS 32
#define TK 32
#define NH (NB*HH)
#define CG 4    // clusters per k_rows block

// ---------------- K1: hash bits -> 32-bit mask per (n,h,l) ----------------
__global__ __launch_bounds__(256) void k_hash(const float* __restrict__ Q,
                                              const float* __restrict__ planes,
                                              unsigned int* __restrict__ qmask) {
    int gid = blockIdx.x * 256 + threadIdx.x;      // nh*LQ + l
    int nh = gid >> 11, l = gid & (LQ - 1);
    int n = nh >> 3, h = nh & 7;
    const float* qrow = Q + (((size_t)n * LQ + l) * HH + h) * EE;
    float q[64];
    #pragma unroll
    for (int e = 0; e < 64; e++) q[e] = qrow[e];
    unsigned int m = 0;
    for (int b = 0; b < NBITS; b++) {
        double acc = (double)planes[b * 65 + 64];   // bias
        #pragma unroll
        for (int e = 0; e < 64; e++) acc += (double)q[e] * (double)planes[b * 65 + e];
        if (acc > 0.0) m |= (1u << b);
    }
    qmask[gid] = m;
}

// ---------------- K2a: centroid init ----------------
__global__ __launch_bounds__(256) void k_cinit(const unsigned int* __restrict__ qmask,
                                               unsigned int* __restrict__ cent_g) {
    int nh = blockIdx.x, t = threadIdx.x;
    cent_g[nh * CC + t] = qmask[(size_t)nh * LQ + t * 8];   // init_idx = c*8
}

// ---------------- K2b: assign (data-parallel, 128 blocks) ----------------
__global__ __launch_bounds__(256) void k_assign(const unsigned int* __restrict__ qmask,
                                                const unsigned int* __restrict__ cent_g,
                                                int* __restrict__ asg) {
    int nh = blockIdx.x >> 3;              // 8 blocks per nh
    int p = ((blockIdx.x & 7) << 8) + threadIdx.x;
    int t = threadIdx.x;
    __shared__ __align__(16) unsigned int cent[CC];
    cent[t] = cent_g[nh * CC + t];
    __syncthreads();
    unsigned int m = qmask[(size_t)nh * LQ + p];
    int best = 0x7fffffff;
    const uint4* c4p = (const uint4*)cent;
    #pragma unroll 4
    for (int c4 = 0; c4 < CC / 4; c4++) {
        uint4 cm = c4p[c4];
        int base = c4 << 2;
        int e0 = (__popc(m ^ cm.x) << 8) + base;
        int e1 = (__popc(m ^ cm.y) << 8) + base + 1;
        int e2 = (__popc(m ^ cm.z) << 8) + base + 2;
        int e3 = (__popc(m ^ cm.w) << 8) + base + 3;
        int e01 = e0 < e1 ? e0 : e1;
        int e23 = e2 < e3 ? e2 : e3;
        int e = e01 < e23 ? e01 : e23;
        best = best < e ? best : e;
    }
    asg[(size_t)nh * LQ + p] = best & 255;
}

// ---------------- K2c: update (per-nh counting sort + exact majority) ----------------
__global__ __launch_bounds__(512) void k_update(const unsigned int* __restrict__ qmask,
                                                const int* __restrict__ asg,
                                                unsigned int* __restrict__ cent_g) {
    int nh = blockIdx.x, t = threadIdx.x;
    __shared__ unsigned int sorted[LQ];               // 8KB
    __shared__ int cnts[CC], offs[CC], cursor[CC];
    if (t < CC) cnts[t] = 0;
    int bc[4]; unsigned int mym[4];
    #pragma unroll
    for (int k = 0; k < 4; k++) {
        bc[k] = asg[(size_t)nh * LQ + t + k * 512];
        mym[k] = qmask[(size_t)nh * LQ + t + k * 512];
    }
    __syncthreads();
    #pragma unroll
    for (int k = 0; k < 4; k++) atomicAdd(&cnts[bc[k]], 1);
    __syncthreads();
    if (t < 64) {                                     // single-wave exclusive scan
        int c0 = cnts[4 * t], c1 = cnts[4 * t + 1], c2 = cnts[4 * t + 2], c3 = cnts[4 * t + 3];
        int s1 = c0 + c1, s2 = s1 + c2, tot = s2 + c3;
        int inc = tot;
        #pragma unroll
        for (int o = 1; o < 64; o <<= 1) {
            int v = __shfl_up(inc, o);
            if (t >= o) inc += v;
        }
        int excl = inc - tot;
        offs[4 * t] = excl;          cursor[4 * t] = excl;
        offs[4 * t + 1] = excl + c0; cursor[4 * t + 1] = excl + c0;
        offs[4 * t + 2] = excl + s1; cursor[4 * t + 2] = excl + s1;
        offs[4 * t + 3] = excl + s2; cursor[4 * t + 3] = excl + s2;
    }
    __syncthreads();
    int cl = t >> 1, j = t & 1;
    int cnt_c = cnts[cl], off_c = offs[cl];
    #pragma unroll
    for (int k = 0; k < 4; k++) {
        int pos = atomicAdd(&cursor[bc[k]], 1);
        sorted[pos] = mym[k];
    }
    __syncthreads();
    int bs[32];
    #pragma unroll
    for (int b = 0; b < 32; b++) bs[b] = 0;
    for (int i = j; i < cnt_c; i += 2) {
        unsigned int m = sorted[off_c + i];
        #pragma unroll
        for (int b = 0; b < 32; b++) bs[b] += (m >> b) & 1;
    }
    #pragma unroll
    for (int b = 0; b < 32; b++) bs[b] += __shfl_xor(bs[b], 1);
    if (j == 0 && cnt_c > 0) {
        unsigned int nc = 0;
        #pragma unroll
        for (int b = 0; b < 32; b++) if (2 * bs[b] >= cnt_c) nc |= (1u << b);
        cent_g[nh * CC + cl] = nc;                    // exact majority; keep old if cnt==0
    }
}

// ---------------- K2d: finalize counts/offsets/order from final assignment ----------------
__global__ __launch_bounds__(512) void k_finalize(const int* __restrict__ asg,
                                                  int* __restrict__ counts_out,
                                                  int* __restrict__ order_out,
                                                  int* __restrict__ offsets_out) {
    int nh = blockIdx.x, t = threadIdx.x;
    __shared__ int cnts[CC], offs[CC], cursor[CC];
    if (t < CC) cnts[t] = 0;
    int bc[4];
    #pragma unroll
    for (int k = 0; k < 4; k++) bc[k] = asg[(size_t)nh * LQ + t + k * 512];
    __syncthreads();
    #pragma unroll
    for (int k = 0; k < 4; k++) atomicAdd(&cnts[bc[k]], 1);
    __syncthreads();
    if (t < 64) {
        int c0 = cnts[4 * t], c1 = cnts[4 * t + 1], c2 = cnts[4 * t + 2], c3 = cnts[4 * t + 3];
        int s1 = c0 + c1, s2 = s1 + c2, tot = s2 + c3;
        int inc = tot;
        #pragma unroll
        for (int o = 1; o < 64; o <<= 1) {
            int v = __shfl_up(inc, o);
            if (t >= o) inc += v;
        }
        int excl = inc - tot;
        offs[4 * t] = excl;          cursor[4 * t] = excl;
        offs[4 * t + 1] = excl + c0; cursor[4 * t + 1] = excl + c0;
        offs[4 * t + 2] = excl + s1; cursor[4 * t + 2] = excl + s1;
        offs[4 * t + 3] = excl + s2; cursor[4 * t + 3] = excl + s2;
    }
    __syncthreads();
    if (t < CC) {
        counts_out[nh * CC + t] = cnts[t];
        offsets_out[nh * CC + t] = offs[t];
    }
    #pragma unroll
    for (int k = 0; k < 4; k++) {
        int pos = atomicAdd(&cursor[bc[k]], 1);
        order_out[(size_t)nh * LQ + pos] = t + k * 512;
    }
}

// ---------------- K3: segmented cluster-mean Qg (f64), wave per cluster ----------------
__global__ __launch_bounds__(256) void k_qg(const float* __restrict__ Q,
                                            const int* __restrict__ order,
                                            const int* __restrict__ offsets,
                                            const int* __restrict__ counts,
                                            double* __restrict__ Qg) {
    int nh = blockIdx.x >> 6;              // 64 blocks per nh
    int c = (blockIdx.x & 63) * 4 + (threadIdx.x >> 6);
    int e = threadIdx.x & 63;
    int n = nh >> 3, h = nh & 7;
    int off = offsets[nh * CC + c];
    int cnt = counts[nh * CC + c];
    const int* ord = order + (size_t)nh * LQ + off;
    double acc = 0.0;
    for (int i = 0; i < cnt; i++) {
        int p = ord[i];                    // wave-uniform broadcast read
        acc += (double)Q[(((size_t)n * LQ + p) * HH + h) * EE + e];
    }
    double safe = cnt > 0 ? (double)cnt : 1.0;
    Qg[((size_t)(nh * CC + c)) * EE + e] = acc / safe;
}

// ---------------- K3b: transpose K -> Kt[nh][e][s] ----------------
__global__ __launch_bounds__(256) void k_transpose(const float* __restrict__ Kp,
                                                   float* __restrict__ Kt) {
    int nh = blockIdx.x >> 5;              // 32 s-tiles of 64
    int s0 = (blockIdx.x & 31) * 64;
    int n = nh >> 3, h = nh & 7;
    __shared__ float tile[64][65];
    int t = threadIdx.x;
    int e = t & 63, r0 = t >> 6;
    #pragma unroll
    for (int j = 0; j < 16; j++) {
        int r = r0 * 16 + j;
        tile[r][e] = Kp[(((size_t)n * SS + s0 + r) * HH + h) * EE + e];
    }
    __syncthreads();
    int sl = t & 63, eg = t >> 6;
    #pragma unroll
    for (int j = 0; j < 16; j++) {
        int ee_ = eg * 16 + j;
        Kt[((size_t)nh * EE + ee_) * SS + s0 + sl] = tile[sl][ee_];
    }
}

// ---------------- K4 v9 (R14 best): chunked LDS transpose (18KB) + XCD swizzle, f64 --
__global__ __launch_bounds__(256) void k_rows(const float* __restrict__ Kt,
                                              const float* __restrict__ Vp,
                                              const double* __restrict__ Qg,
                                              int* __restrict__ topi,
                                              float* __restrict__ abk,
                                              float* __restrict__ Vg) {
    int bid = blockIdx.x;
    int xcd = bid & 7, idx = bid >> 3;     // XCD-chunked: xcd owns 2 nh slices (L2-local)
    int nh = xcd * 2 + (idx >> 6);
    int cg = idx & 63;
    int c0 = cg * CG;
    int n = nh >> 3, h = nh & 7;
    int t = threadIdx.x, w = t >> 6, l = t & 63;

    __shared__ double qgl[EE][CG];         // 2KB
    __shared__ double xrowc[CG][512];      // 16KB chunk buffer (reused 4x)
    float* wbuf = (float*)&xrowc[0][0];    // [512][CG] f32 = 8KB overlay
    float* redv = (float*)&xrowc[2][0];    // 4KB (disjoint from wbuf)

    qgl[t >> 2][t & 3] = Qg[((size_t)(nh * CC + c0 + (t & 3))) * EE + (t >> 2)];
    __syncthreads();

    // ---- phase A: QK scores (f64) in registers, coalesced Kt reads ----
    double acc[8][CG];
    #pragma unroll
    for (int r = 0; r < 8; r++)
        #pragma unroll
        for (int c = 0; c < CG; c++) acc[r][c] = 0.0;
    const float* ktb = Kt + ((size_t)nh * EE) * SS + t;
    for (int e = 0; e < EE; e++) {
        double q0 = qgl[e][0], q1 = qgl[e][1], q2 = qgl[e][2], q3 = qgl[e][3];
        const float* kr = ktb + (size_t)e * SS;
        #pragma unroll
        for (int r = 0; r < 8; r++) {
            double kv = (double)kr[r * 256];
            acc[r][0] += q0 * kv; acc[r][1] += q1 * kv;
            acc[r][2] += q2 * kv; acc[r][3] += q3 * kv;
        }
    }

    // ---- chunked transpose: acc -> v[32] (v[k] = score(c=w, s=l+64k)) ----
    double v[32];
    #pragma unroll
    for (int j = 0; j < 4; j++) {
        __syncthreads();
        #pragma unroll
        for (int c = 0; c < CG; c++) {
            xrowc[c][t]       = acc[2 * j][c];
            xrowc[c][256 + t] = acc[2 * j + 1][c];
        }
        __syncthreads();
        #pragma unroll
        for (int m = 0; m < 8; m++)
            v[8 * j + m] = xrowc[w][((m >> 2) << 8) + ((m & 3) << 6) + l];
    }

    // ---- phase B: max, denom, top-32 (exact f64, ties -> lowest s) ----
    double m = v[0];
    #pragma unroll
    for (int k = 1; k < 32; k++) m = v[k] > m ? v[k] : m;
    #pragma unroll
    for (int o = 32; o > 0; o >>= 1) { double z = __shfl_xor(m, o); m = z > m ? z : m; }

    double ds = 0.0;
    #pragma unroll
    for (int k = 0; k < 32; k++) ds += (double)expf(0.125f * (float)(v[k] - m));
    #pragma unroll
    for (int o = 32; o > 0; o >>= 1) ds += __shfl_xor(ds, o);

    unsigned ext = 0;
    double lbv = -1e301; int lbi = 1 << 30;
    #pragma unroll
    for (int k = 0; k < 32; k++)
        if (v[k] > lbv) { lbv = v[k]; lbi = l + k * 64; }
    double topsum = 0.0;
    int rowid = nh * CC + c0 + w;
    for (int kk = 0; kk < TK; kk++) {
        double bv = lbv; int bi = lbi;
        #pragma unroll
        for (int o = 32; o > 0; o >>= 1) {
            double v2 = __shfl_xor(bv, o); int i2 = __shfl_xor(bi, o);
            if (v2 > bv || (v2 == bv && i2 < bi)) { bv = v2; bi = i2; }
        }
        topsum += (double)expf(0.125f * (float)(bv - m));
        if (l == 0) topi[(size_t)rowid * TK + kk] = bi;
        if ((bi & 63) == l) {
            ext |= 1u << (bi >> 6);
            lbv = -1e301; lbi = 1 << 30;
            #pragma unroll
            for (int k = 0; k < 32; k++)
                if (!((ext >> k) & 1) && v[k] > lbv) { lbv = v[k]; lbi = l + k * 64; }
        }
    }
    if (l == 0) abk[rowid] = (float)((ds - topsum) / ds);

    float invd = (float)(1.0 / ds);
    float w32r[32];
    #pragma unroll
    for (int k = 0; k < 32; k++)
        w32r[k] = ((ext >> k) & 1) ? 0.0f
                : expf(0.125f * (float)(v[k] - m)) * invd;

    // ---- phase C: chunked weight exchange + Vg accumulate ----
    float a0 = 0.f, a1 = 0.f, a2 = 0.f, a3 = 0.f;
    const float* vb = Vp + (((size_t)n * SS) * HH + h) * EE + l;   // e = l
    #pragma unroll
    for (int j = 0; j < 4; j++) {
        __syncthreads();
        #pragma unroll
        for (int m2 = 0; m2 < 8; m2++)
            wbuf[(((m2 << 6) + l) << 2) + w] = w32r[8 * j + m2];
        __syncthreads();
        const float4* wp4 = (const float4*)wbuf;
        int sbase = 512 * j + 128 * w;
        for (int s = 0; s < 128; s++) {
            float4 wv = wp4[128 * w + s];                          // wave-uniform broadcast
            float vv = vb[(size_t)(sbase + s) * HH * EE];          // coalesced (e=l)
            a0 += wv.x * vv; a1 += wv.y * vv; a2 += wv.z * vv; a3 += wv.w * vv;
        }
    }
    {
        int e = l, grp = w;
        redv[(grp * 4 + 0) * 64 + e] = a0;
        redv[(grp * 4 + 1) * 64 + e] = a1;
        redv[(grp * 4 + 2) * 64 + e] = a2;
        redv[(grp * 4 + 3) * 64 + e] = a3;
        __syncthreads();
        int c = w;
        float s = redv[(0 * 4 + c) * 64 + e] + redv[(1 * 4 + c) * 64 + e]
                + redv[(2 * 4 + c) * 64 + e] + redv[(3 * 4 + c) * 64 + e];
        Vg[((size_t)(nh * CC + c0 + c)) * EE + e] = s;
    }
}

// ---------------- K5: per-query top-32 re-attention + V_bottom ----------------
__global__ __launch_bounds__(256) void k_out(const float* __restrict__ Q,
                                             const float* __restrict__ Kp,
                                             const float* __restrict__ Vp,
                                             const int* __restrict__ clusters,
                                             const int* __restrict__ topi,
                                             const float* __restrict__ abk,
                                             const float* __restrict__ Vg,
                                             float* __restrict__ out) {
    int tid = threadIdx.x, wid = tid >> 6, e = tid & 63;
    int q = blockIdx.x * 4 + wid;            // nh*LQ + l
    int nh = q >> 11, l = q & (LQ - 1);
    int n = nh >> 3, h = nh & 7;
    int c = clusters[q];
    float scale = 1.0f - abk[nh * CC + c];
    const int* ti = topi + (size_t)(nh * CC + c) * TK;
    float qe = Q[(((size_t)n * LQ + l) * HH + h) * EE + e];
    float myv = -INFINITY;
    for (int k = 0; k < TK; k++) {
        int idx = ti[k];
        float kv = Kp[(((size_t)n * SS + idx) * HH + h) * EE + e];
        float v = qe * kv;
        #pragma unroll
        for (int o = 32; o > 0; o >>= 1) v += __shfl_xor(v, o);
        if (e == k) myv = v;
    }
    float mv = myv;
    #pragma unroll
    for (int o = 32; o > 0; o >>= 1) { float v = __shfl_xor(mv, o); mv = v > mv ? v : mv; }
    float p = (e < TK) ? expf(0.125f * (myv - mv)) : 0.0f;
    float ssum = p;
    #pragma unroll
    for (int o = 32; o > 0; o >>= 1) ssum += __shfl_xor(ssum, o);
    float at = p / ssum * scale;
    float acc = 0.0f;
    for (int k = 0; k < TK; k++) {
        float wk = __shfl(at, k, 64);
        int idx = ti[k];
        acc += wk * Vp[(((size_t)n * SS + idx) * HH + h) * EE + e];
    }
    acc += Vg[(size_t)(nh * CC + c) * EE + e];
    out[(((size_t)n * LQ + l) * HH + h) * EE + e] = acc;
}

extern "C" void kernel_launch(void* const* d_in, const int* in_sizes, int n_in,
                              void* d_out, int out_size, void* d_ws, size_t ws_size,
                              hipStream_t stream) {
    const float* Q      = (const float*)d_in[0];
    const float* K      = (const float*)d_in[1];
    const float* V      = (const float*)d_in[2];
    const float* planes = (const float*)d_in[3];
    float* out = (float*)d_out;

    char* ws = (char*)d_ws;
    unsigned int* qmask    = (unsigned int*)(ws);                   // 128KB
    int*          clusters = (int*)(ws + (128 << 10));              // 128KB (= asg)
    int*          counts   = (int*)(ws + (256 << 10));              // 16KB
    float*        abk      = (float*)(ws + (272 << 10));            // 16KB
    int*          topi     = (int*)(ws + (288 << 10));              // 512KB
    float*        Vg       = (float*)(ws + (800 << 10));            // 1MB
    double*       Qg       = (double*)(ws + (1824 << 10));          // 2MB
    float*        Kt       = (float*)(ws + (4096 << 10));           // 8MB  [4MB,12MB)
    int*          order    = (int*)(ws + (12288 << 10));            // 128KB
    int*          offsets  = (int*)(ws + (12416 << 10));            // 16KB
    unsigned int* cent_g   = (unsigned int*)(ws + (12432 << 10));   // 16KB

    k_transpose<<<dim3(NH * 32), dim3(256), 0, stream>>>(K, Kt);
    k_hash<<<dim3(NH * LQ / 256), dim3(256), 0, stream>>>(Q, planes, qmask);
    k_cinit<<<dim3(NH), dim3(256), 0, stream>>>(qmask, cent_g);
    for (int it = 0; it < KM_ITERS; ++it) {
        k_assign<<<dim3(NH * 8), dim3(256), 0, stream>>>(qmask, cent_g, clusters);
        k_update<<<dim3(NH), dim3(512), 0, stream>>>(qmask, clusters, cent_g);
    }
    k_assign<<<dim3(NH * 8), dim3(256), 0, stream>>>(qmask, cent_g, clusters);
    k_finalize<<<dim3(NH), dim3(512), 0, stream>>>(clusters, counts, order, offsets);
    k_qg<<<dim3(NH * 64), dim3(256), 0, stream>>>(Q, order, offsets, counts, Qg);
    k_rows<<<dim3(NH * CC / CG), dim3(256), 0, stream>>>(Kt, V, Qg, topi, abk, Vg);
    k_out<<<dim3(NH * LQ / 4), dim3(256), 0, stream>>>(Q, K, V, clusters, topi, abk, Vg, out);
}